// Round 4
// baseline (107.501 us; speedup 1.0000x reference)
//
#include <hip/hip_runtime.h>

// Dynamic lightweight convolution. B=8, S=2048, D=1024, K=7, H=16, L=2042.
// K0: WtFrag[i=7][ks=32][lane=64] x 8 bf16 = W[ks*32+(lane>>4)*8+j][i*16+(lane&15)]
// K1: per block (16 rows): stage A full-K in LDS -> wave0 MFMA GEMM + in-reg
//     softmax -> P in LDS -> all waves streaming conv.

#define KK 7
#define HH 16
#define DD 1024
#define SS 2048
#define LL 2042
#define NO 112
#define TL 16
#define WTF_ELEMS (7 * 32 * 64 * 8)          // 114688 bf16
#define WTF_BYTES (WTF_ELEMS * 2)            // 229376

typedef __attribute__((ext_vector_type(8))) short bf16x8;
typedef __attribute__((ext_vector_type(4))) float f32x4;

__device__ __forceinline__ unsigned short f2bf(float f) {
    unsigned u = __builtin_bit_cast(unsigned, f);
    u += 0x7fffu + ((u >> 16) & 1u);         // RNE
    return (unsigned short)(u >> 16);
}
__device__ __forceinline__ unsigned bfpack(float lo, float hi) {
    return (unsigned)f2bf(lo) | ((unsigned)f2bf(hi) << 16);
}

__global__ void wprep(const float* __restrict__ W, unsigned short* __restrict__ wtf) {
    const int bx = blockIdx.x;               // 0..223 = i*32 + ks
    const int lane = threadIdx.x;            // 0..63
    const int i = bx >> 5, ks = bx & 31;
    const int frow = lane & 15, fq = lane >> 4;
    const int col = i * 16 + frow;
    const int k0 = ks * 32 + fq * 8;
    unsigned p[4];
#pragma unroll
    for (int j = 0; j < 4; ++j) {
        float a = W[(size_t)(k0 + 2 * j) * NO + col];
        float b = W[(size_t)(k0 + 2 * j + 1) * NO + col];
        p[j] = bfpack(a, b);
    }
    *(uint4*)(wtf + (size_t)(bx * 64 + lane) * 8) = make_uint4(p[0], p[1], p[2], p[3]);
}

// LDS: A bf16 [16][1024] swizzled @0..32768 ; P f32 [16][7][16] @32768..39936
template <bool WSOK>
__global__ __launch_bounds__(512, 6)
void dlconv(const float* __restrict__ x, const float* __restrict__ W,
            const float* __restrict__ bias, const unsigned short* __restrict__ wtf,
            float* __restrict__ out)
{
    __shared__ __align__(16) unsigned char smem[39936];
    float* P = (float*)(smem + 32768);
    const int t  = threadIdx.x;
    const int lb = blockIdx.x, b = blockIdx.y;
    const int l0 = lb * TL;
    const float* xb = x + (size_t)b * SS * DD;

    // ---- stage A: rows l0+6..l0+21, all 1024 k, bf16, XOR-swizzled ----
#pragma unroll
    for (int s = 0; s < 8; ++s) {
        int idx = t + 512 * s;               // 0..4095 = 16 rows x 256 float4
        int row = idx >> 8, c4 = idx & 255;
        int gr = l0 + 6 + row; gr = gr < SS ? gr : SS - 1;
        float4 v = *(const float4*)(xb + (size_t)gr * DD + c4 * 4);
        int addr = row * 2048 + ((c4 * 8) ^ ((row & 7) << 4));
        *(uint2*)(smem + addr) = make_uint2(bfpack(v.x, v.y), bfpack(v.z, v.w));
    }
    __syncthreads();

    if (t < 64) {
        // ---- wave 0: GEMM 16 x 112, K=1024 ----
        const int lane = t;
        const int frow = lane & 15, fq = lane >> 4;
        f32x4 acc[KK];
#pragma unroll
        for (int i = 0; i < KK; ++i) acc[i] = (f32x4)0.f;
        for (int ks = 0; ks < 32; ++ks) {
            int kbyte = ks * 64 + fq * 16;
            bf16x8 af = *(const bf16x8*)(smem + frow * 2048 + (kbyte ^ ((frow & 7) << 4)));
#pragma unroll
            for (int i = 0; i < KK; ++i) {
                bf16x8 bf;
                if constexpr (WSOK) {
                    bf = *(const bf16x8*)(wtf + (size_t)((i * 32 + ks) * 64 + lane) * 8);
                } else {
                    const float* wp = W + (size_t)(ks * 32 + fq * 8) * NO + i * 16 + frow;
                    short e0 = (short)f2bf(wp[0 * NO]), e1 = (short)f2bf(wp[1 * NO]);
                    short e2 = (short)f2bf(wp[2 * NO]), e3 = (short)f2bf(wp[3 * NO]);
                    short e4 = (short)f2bf(wp[4 * NO]), e5 = (short)f2bf(wp[5 * NO]);
                    short e6 = (short)f2bf(wp[6 * NO]), e7 = (short)f2bf(wp[7 * NO]);
                    bf = bf16x8{e0, e1, e2, e3, e4, e5, e6, e7};
                }
                acc[i] = __builtin_amdgcn_mfma_f32_16x16x32_bf16(af, bf, acc[i], 0, 0, 0);
            }
        }
        // ---- softmax over k, in registers: rows fq*4+reg, head frow ----
#pragma unroll
        for (int reg = 0; reg < 4; ++reg) {
            int r = fq * 4 + reg;
            float v[KK];
            float m = -1e30f;
#pragma unroll
            for (int i = 0; i < KK; ++i) {
                v[i] = acc[i][reg] + bias[i * 16 + frow];
                m = fmaxf(m, v[i]);
            }
            float ssum = 0.f;
#pragma unroll
            for (int i = 0; i < KK; ++i) { v[i] = __expf(v[i] - m); ssum += v[i]; }
            float inv = 1.f / (7.f * ssum);
#pragma unroll
            for (int i = 0; i < KK; ++i) P[(r * KK + i) * 16 + frow] = v[i] * inv;
        }
    }
    __syncthreads();

    // ---- conv: 512 threads, 16 rows x 1024 d; thread: row t>>5, 8 float4 ----
    const int r = t >> 5, c = t & 31;
    if (l0 + r < LL) {
        const float* xr = xb + (size_t)(l0 + r) * DD + c * 4;
        float* orow = out + ((size_t)b * LL + l0 + r) * DD + c * 4;
        const float* Pr = P + r * KK * 16 + (c & 3) * 4;
#pragma unroll
        for (int jj = 0; jj < 4; ++jj) {
            f32x4 o0 = (f32x4)0.f, o1 = (f32x4)0.f;
#pragma unroll
            for (int k = 0; k < KK; ++k) {
                f32x4 pv = *(const f32x4*)(Pr + k * 16);
                f32x4 x0 = *(const f32x4*)(xr + (size_t)k * DD + jj * 256);
                f32x4 x1 = *(const f32x4*)(xr + (size_t)k * DD + jj * 256 + 128);
                o0 += pv * x0;
                o1 += pv * x1;
            }
            *(f32x4*)(orow + jj * 256) = o0;
            *(f32x4*)(orow + jj * 256 + 128) = o1;
        }
    }
}

extern "C" void kernel_launch(void* const* d_in, const int* in_sizes, int n_in,
                              void* d_out, int out_size, void* d_ws, size_t ws_size,
                              hipStream_t stream) {
    const float* x    = (const float*)d_in[0];
    const float* W    = (const float*)d_in[1];
    const float* bias = (const float*)d_in[2];
    float* out        = (float*)d_out;
    dim3 grid((LL + TL - 1) / TL, 8);        // 128 x 8 = 1024 blocks
    const bool wsok = (ws_size >= (size_t)WTF_BYTES) && d_ws != nullptr;
    if (wsok) {
        unsigned short* wtf = (unsigned short*)d_ws;
        wprep<<<224, 64, 0, stream>>>(W, wtf);
        dlconv<true><<<grid, 512, 0, stream>>>(x, W, bias, wtf, out);
    } else {
        dlconv<false><<<grid, 512, 0, stream>>>(x, W, bias, nullptr, out);
    }
}

// Round 5
// 61.081 us; speedup vs baseline: 1.7600x; 1.7600x over previous
//
#include <hip/hip_runtime.h>

// Dynamic lightweight convolution. B=8, S=2048, D=1024, K=7, H=16, L=2042.
// K0 (wprep): WtFrag[i=7][ks=32][lane=64] x 8bf16 = W[ks*32+(lane>>4)*8+j][i*16+(lane&15)]
// K1 (dlconv), per block = 16 rows:
//   stage A (bf16, XOR-swz, 32KB LDS) -> waves 0..6 each MFMA one n-tile (k=i)
//   -> logits via LDS -> 256-thread softmax -> P -> all-wave streaming conv.

#define KK 7
#define HH 16
#define DD 1024
#define SS 2048
#define LL 2042
#define NO 112
#define TL 16
#define WTF_ELEMS (7 * 32 * 64 * 8)          // 114688 bf16
#define WTF_BYTES (WTF_ELEMS * 2)            // 229376

typedef __attribute__((ext_vector_type(8))) short bf16x8;
typedef __attribute__((ext_vector_type(4))) float f32x4;

__device__ __forceinline__ unsigned short f2bf(float f) {
    unsigned u = __builtin_bit_cast(unsigned, f);
    u += 0x7fffu + ((u >> 16) & 1u);         // RNE
    return (unsigned short)(u >> 16);
}
__device__ __forceinline__ unsigned bfpack(float lo, float hi) {
    return (unsigned)f2bf(lo) | ((unsigned)f2bf(hi) << 16);
}

__global__ void wprep(const float* __restrict__ W, unsigned short* __restrict__ wtf) {
    const int bx = blockIdx.x;               // 0..223 = i*32 + ks
    const int lane = threadIdx.x;            // 0..63
    const int i = bx >> 5, ks = bx & 31;
    const int frow = lane & 15, fq = lane >> 4;
    const int col = i * 16 + frow;
    const int k0 = ks * 32 + fq * 8;
    unsigned p[4];
#pragma unroll
    for (int j = 0; j < 4; ++j) {
        float a = W[(size_t)(k0 + 2 * j) * NO + col];
        float b = W[(size_t)(k0 + 2 * j + 1) * NO + col];
        p[j] = bfpack(a, b);
    }
    *(uint4*)(wtf + (size_t)(bx * 64 + lane) * 8) = make_uint4(p[0], p[1], p[2], p[3]);
}

// LDS (32768 B):
//   phase 1-2: A bf16 [16][1024] XOR-swizzled, rows at 2048 B stride
//   phase 3+ (A dead, after barrier): Lg f32 [16][116] @0 ; P f32 [16][7][16] @8192
template <bool WSOK>
__global__ __launch_bounds__(512, 8)
void dlconv(const float* __restrict__ x, const float* __restrict__ W,
            const float* __restrict__ bias, const unsigned short* __restrict__ wtf,
            float* __restrict__ out)
{
    __shared__ __align__(16) unsigned char smem[32768];
    float* Lg = (float*)smem;                // [16][116]
    float* P  = (float*)(smem + 8192);       // [16][7][16]
    const int t  = threadIdx.x;
    const int lb = blockIdx.x, b = blockIdx.y;
    const int l0 = lb * TL;
    const float* xb = x + (size_t)b * SS * DD;

    // ---- stage A: rows l0+6..l0+21, all 1024 k, bf16, XOR-swizzled ----
#pragma unroll
    for (int s = 0; s < 8; ++s) {
        int idx = t + 512 * s;               // 0..4095 = 16 rows x 256 float4
        int row = idx >> 8, c4 = idx & 255;
        int gr = l0 + 6 + row; gr = gr < SS ? gr : SS - 1;
        float4 v = *(const float4*)(xb + (size_t)gr * DD + c4 * 4);
        int addr = row * 2048 + ((c4 * 8) ^ ((row & 7) << 4));
        *(uint2*)(smem + addr) = make_uint2(bfpack(v.x, v.y), bfpack(v.z, v.w));
    }
    __syncthreads();

    // ---- GEMM: wave i (i<7) computes n-tile i (softmax index k=i) ----
    const int lane = t & 63, wid = t >> 6;
    const int frow = lane & 15, fq = lane >> 4;
    f32x4 acc = (f32x4)0.f;
    if (wid < 7) {
#pragma unroll 4
        for (int ks = 0; ks < 32; ++ks) {
            bf16x8 af = *(const bf16x8*)(smem + frow * 2048 +
                                         ((ks * 64 + fq * 16) ^ ((frow & 7) << 4)));
            bf16x8 bf;
            if constexpr (WSOK) {
                bf = *(const bf16x8*)(wtf + (size_t)((wid * 32 + ks) * 64 + lane) * 8);
            } else {
                const float* wp = W + (size_t)(ks * 32 + fq * 8) * NO + wid * 16 + frow;
                short e0 = (short)f2bf(wp[0 * NO]), e1 = (short)f2bf(wp[1 * NO]);
                short e2 = (short)f2bf(wp[2 * NO]), e3 = (short)f2bf(wp[3 * NO]);
                short e4 = (short)f2bf(wp[4 * NO]), e5 = (short)f2bf(wp[5 * NO]);
                short e6 = (short)f2bf(wp[6 * NO]), e7 = (short)f2bf(wp[7 * NO]);
                bf = bf16x8{e0, e1, e2, e3, e4, e5, e6, e7};
            }
            acc = __builtin_amdgcn_mfma_f32_16x16x32_bf16(af, bf, acc, 0, 0, 0);
        }
    }
    __syncthreads();                          // A region dead beyond this point

    // ---- logits (+bias) -> Lg[r][i*16+h], stride 116 ----
    if (wid < 7) {
        float bi = bias[wid * 16 + frow];
#pragma unroll
        for (int reg = 0; reg < 4; ++reg)
            Lg[(fq * 4 + reg) * 116 + wid * 16 + frow] = acc[reg] + bi;
    }
    __syncthreads();

    // ---- softmax over k: thread (r = t>>4, h = t&15), 256 threads ----
    if (t < 256) {
        const int r = t >> 4, h = t & 15;
        float v[KK];
        float m = -1e30f;
#pragma unroll
        for (int i = 0; i < KK; ++i) {
            v[i] = Lg[r * 116 + i * 16 + h];
            m = fmaxf(m, v[i]);
        }
        float ssum = 0.f;
#pragma unroll
        for (int i = 0; i < KK; ++i) { v[i] = __expf(v[i] - m); ssum += v[i]; }
        float inv = 1.f / (7.f * ssum);       // fold mean's 1/7
#pragma unroll
        for (int i = 0; i < KK; ++i) P[(r * KK + i) * 16 + h] = v[i] * inv;
    }
    __syncthreads();

    // ---- conv: out[b,l0+r,d] = sum_k P[r][k][d%16] * x[b,l0+r+k,d] ----
    const int r = t >> 5, c = t & 31;
    if (l0 + r < LL) {
        const float* xr = xb + (size_t)(l0 + r) * DD + c * 4;
        float* orow = out + ((size_t)b * LL + l0 + r) * DD + c * 4;
        const float* Pr = P + r * KK * 16 + (c & 3) * 4;
#pragma unroll
        for (int jj = 0; jj < 4; ++jj) {
            f32x4 o0 = (f32x4)0.f, o1 = (f32x4)0.f;
#pragma unroll
            for (int k = 0; k < KK; ++k) {
                f32x4 pv = *(const f32x4*)(Pr + k * 16);
                f32x4 x0 = *(const f32x4*)(xr + (size_t)k * DD + jj * 256);
                f32x4 x1 = *(const f32x4*)(xr + (size_t)k * DD + jj * 256 + 128);
                o0 += pv * x0;
                o1 += pv * x1;
            }
            *(f32x4*)(orow + jj * 256) = o0;
            *(f32x4*)(orow + jj * 256 + 128) = o1;
        }
    }
}

extern "C" void kernel_launch(void* const* d_in, const int* in_sizes, int n_in,
                              void* d_out, int out_size, void* d_ws, size_t ws_size,
                              hipStream_t stream) {
    const float* x    = (const float*)d_in[0];
    const float* W    = (const float*)d_in[1];
    const float* bias = (const float*)d_in[2];
    float* out        = (float*)d_out;
    dim3 grid((LL + TL - 1) / TL, 8);        // 128 x 8 = 1024 blocks
    const bool wsok = (ws_size >= (size_t)WTF_BYTES) && d_ws != nullptr;
    if (wsok) {
        unsigned short* wtf = (unsigned short*)d_ws;
        wprep<<<224, 64, 0, stream>>>(W, wtf);
        dlconv<true><<<grid, 512, 0, stream>>>(x, W, bias, wtf, out);
    } else {
        dlconv<false><<<grid, 512, 0, stream>>>(x, W, bias, nullptr, out);
    }
}

// Round 6
// 55.781 us; speedup vs baseline: 1.9272x; 1.0950x over previous
//
#include <hip/hip_runtime.h>

// Dynamic lightweight convolution. B=8, S=2048, D=1024, K=7, H=16, L=2042.
// K0 (wprep): WtFrag[i=7][ks=32][lane=64] x 8bf16 = W[ks*32+(lane>>4)*8+j][i*16+(lane&15)]
// K1 (dlconv), per block = 16 rows:
//   issue stage-A loads -> issue conv-x prefetch (14 float4, held in regs across
//   all phases) -> LDS-write A -> waves 0..6 MFMA one n-tile each -> logits ->
//   softmax -> P -> conv = pure LDS(P) + FMA on prefetched x.

#define KK 7
#define HH 16
#define DD 1024
#define SS 2048
#define LL 2042
#define NO 112
#define TL 16
#define WTF_ELEMS (7 * 32 * 64 * 8)          // 114688 bf16
#define WTF_BYTES (WTF_ELEMS * 2)            // 229376

typedef __attribute__((ext_vector_type(8))) short bf16x8;
typedef __attribute__((ext_vector_type(4))) float f32x4;

__device__ __forceinline__ unsigned short f2bf(float f) {
    unsigned u = __builtin_bit_cast(unsigned, f);
    u += 0x7fffu + ((u >> 16) & 1u);         // RNE
    return (unsigned short)(u >> 16);
}
__device__ __forceinline__ unsigned bfpack(float lo, float hi) {
    return (unsigned)f2bf(lo) | ((unsigned)f2bf(hi) << 16);
}

__global__ void wprep(const float* __restrict__ W, unsigned short* __restrict__ wtf) {
    const int bx = blockIdx.x;               // 0..223 = i*32 + ks
    const int lane = threadIdx.x;            // 0..63
    const int i = bx >> 5, ks = bx & 31;
    const int frow = lane & 15, fq = lane >> 4;
    const int col = i * 16 + frow;
    const int k0 = ks * 32 + fq * 8;
    unsigned p[4];
#pragma unroll
    for (int j = 0; j < 4; ++j) {
        float a = W[(size_t)(k0 + 2 * j) * NO + col];
        float b = W[(size_t)(k0 + 2 * j + 1) * NO + col];
        p[j] = bfpack(a, b);
    }
    *(uint4*)(wtf + (size_t)(bx * 64 + lane) * 8) = make_uint4(p[0], p[1], p[2], p[3]);
}

// LDS (32768 B):
//   phase 1-2: A bf16 [16][1024] XOR-swizzled, rows at 2048 B stride
//   phase 3+ (A dead): Lg f32 [16][116] @0 ; P f32 [16][7][16] @8192
template <bool WSOK>
__global__ __launch_bounds__(512, 4)
void dlconv(const float* __restrict__ x, const float* __restrict__ W,
            const float* __restrict__ bias, const unsigned short* __restrict__ wtf,
            float* __restrict__ out)
{
    __shared__ __align__(16) unsigned char smem[32768];
    float* Lg = (float*)smem;                // [16][116]
    float* P  = (float*)(smem + 8192);       // [16][7][16]
    const int t  = threadIdx.x;
    const int lb = blockIdx.x, b = blockIdx.y;
    const int l0 = lb * TL;
    const float* xb = x + (size_t)b * SS * DD;

    // conv-thread mapping: row-group rg (8 rows), channel block d0 (float4)
    const int rg = t >> 8;                   // 0..1
    const int cc = t & 255;                  // 0..255
    const int d0 = cc << 2;                  // 0..1020
    const int hs = (cc & 3) << 2;            // P h-slice offset (floats)

    // ---- 1) stage-A loads -> regs (rows l0+6..l0+21, all K) ----
    float4 sx[8];
#pragma unroll
    for (int s = 0; s < 8; ++s) {
        int idx = t + 512 * s;               // 16 rows x 256 float4
        int row = idx >> 8, c4 = idx & 255;
        int gr = l0 + 6 + row; gr = gr < SS ? gr : SS - 1;
        sx[s] = *(const float4*)(xb + (size_t)gr * DD + c4 * 4);
    }
    // ---- 2) conv x prefetch: rows l0+rg*8 .. +13, held across all phases ----
    float4 cx[14];
#pragma unroll
    for (int j = 0; j < 14; ++j) {
        int gr = l0 + rg * 8 + j; gr = gr < SS ? gr : SS - 1;
        cx[j] = *(const float4*)(xb + (size_t)gr * DD + d0);
    }
    // ---- 3) A -> LDS (bf16, XOR-swizzled); waits only on sx batch ----
#pragma unroll
    for (int s = 0; s < 8; ++s) {
        int idx = t + 512 * s;
        int row = idx >> 8, c4 = idx & 255;
        int addr = row * 2048 + ((c4 * 8) ^ ((row & 7) << 4));
        *(uint2*)(smem + addr) = make_uint2(bfpack(sx[s].x, sx[s].y), bfpack(sx[s].z, sx[s].w));
    }
    __syncthreads();

    // ---- GEMM: wave i (i<7) computes n-tile i (softmax index k=i) ----
    const int lane = t & 63, wid = t >> 6;
    const int frow = lane & 15, fq = lane >> 4;
    f32x4 acc = (f32x4)0.f;
    if (wid < 7) {
#pragma unroll 8
        for (int ks = 0; ks < 32; ++ks) {
            bf16x8 af = *(const bf16x8*)(smem + frow * 2048 +
                                         ((ks * 64 + fq * 16) ^ ((frow & 7) << 4)));
            bf16x8 bf;
            if constexpr (WSOK) {
                bf = *(const bf16x8*)(wtf + (size_t)((wid * 32 + ks) * 64 + lane) * 8);
            } else {
                const float* wp = W + (size_t)(ks * 32 + fq * 8) * NO + wid * 16 + frow;
                short e0 = (short)f2bf(wp[0 * NO]), e1 = (short)f2bf(wp[1 * NO]);
                short e2 = (short)f2bf(wp[2 * NO]), e3 = (short)f2bf(wp[3 * NO]);
                short e4 = (short)f2bf(wp[4 * NO]), e5 = (short)f2bf(wp[5 * NO]);
                short e6 = (short)f2bf(wp[6 * NO]), e7 = (short)f2bf(wp[7 * NO]);
                bf = bf16x8{e0, e1, e2, e3, e4, e5, e6, e7};
            }
            acc = __builtin_amdgcn_mfma_f32_16x16x32_bf16(af, bf, acc, 0, 0, 0);
        }
    }
    __syncthreads();                          // A region dead beyond this point

    // ---- logits (+bias) -> Lg[r][i*16+h], stride 116 ----
    if (wid < 7) {
        float bi = bias[wid * 16 + frow];
#pragma unroll
        for (int reg = 0; reg < 4; ++reg)
            Lg[(fq * 4 + reg) * 116 + wid * 16 + frow] = acc[reg] + bi;
    }
    __syncthreads();

    // ---- softmax over k: thread (r = t>>4, h = t&15), 256 threads ----
    if (t < 256) {
        const int r = t >> 4, h = t & 15;
        float v[KK];
        float m = -1e30f;
#pragma unroll
        for (int i = 0; i < KK; ++i) {
            v[i] = Lg[r * 116 + i * 16 + h];
            m = fmaxf(m, v[i]);
        }
        float ssum = 0.f;
#pragma unroll
        for (int i = 0; i < KK; ++i) { v[i] = __expf(v[i] - m); ssum += v[i]; }
        float inv = 1.f / (7.f * ssum);       // fold mean's 1/7
#pragma unroll
        for (int i = 0; i < KK; ++i) P[(r * KK + i) * 16 + h] = v[i] * inv;
    }
    __syncthreads();

    // ---- conv: out[b,l0+rg*8+q,d0..] = sum_k P[row][k][hs..] * cx[q+k] ----
#pragma unroll
    for (int q = 0; q < 8; ++q) {
        int row = rg * 8 + q;
        if (l0 + row < LL) {
            f32x4 o = (f32x4)0.f;
#pragma unroll
            for (int k = 0; k < KK; ++k) {
                f32x4 pv = *(const f32x4*)(P + (row * KK + k) * 16 + hs);
                f32x4 xv = { cx[q + k].x, cx[q + k].y, cx[q + k].z, cx[q + k].w };
                o += pv * xv;
            }
            *(f32x4*)(out + ((size_t)b * LL + l0 + row) * DD + d0) = o;
        }
    }
}

extern "C" void kernel_launch(void* const* d_in, const int* in_sizes, int n_in,
                              void* d_out, int out_size, void* d_ws, size_t ws_size,
                              hipStream_t stream) {
    const float* x    = (const float*)d_in[0];
    const float* W    = (const float*)d_in[1];
    const float* bias = (const float*)d_in[2];
    float* out        = (float*)d_out;
    dim3 grid((LL + TL - 1) / TL, 8);        // 128 x 8 = 1024 blocks
    const bool wsok = (ws_size >= (size_t)WTF_BYTES) && d_ws != nullptr;
    if (wsok) {
        unsigned short* wtf = (unsigned short*)d_ws;
        wprep<<<224, 64, 0, stream>>>(W, wtf);
        dlconv<true><<<grid, 512, 0, stream>>>(x, W, bias, wtf, out);
    } else {
        dlconv<false><<<grid, 512, 0, stream>>>(x, W, bias, nullptr, out);
    }
}